// Round 12
// baseline (601.810 us; speedup 1.0000x reference)
//
#include <hip/hip_runtime.h>
#include <math.h>

// Problem constants (N=2, C=64, H=96, W=96, PATCH=3)
static constexpr int NITEM = 2;
static constexpr int C = 64;
static constexpr int W = 96;
static constexpr int H = 96;
static constexpr int HW = H * W;        // 9216
static constexpr int HP = 94;           // H - 3 + 1
static constexpr int NP = HP * HP;      // 8836

// Work units: per (n, dy) split the valid yi-range into PL-row pieces.
static constexpr int PL = 8;
static constexpr int UNITS_PER_N = 1188;
static constexpr int NBLOCKS = 768;     // 3 blocks/CU x 256 CUs

typedef float f32x2 __attribute__((ext_vector_type(2)));

// Packed fp32 FMA with per-element fma semantics (bit-identical to scalar fmaf
// chains). Compiler lowers <2 x float> llvm.fma to v_pk_fma_f32 on gfx950.
#if defined(__has_builtin) && __has_builtin(__builtin_elementwise_fma)
#define VFMA(q, a, b) (q) = __builtin_elementwise_fma((a), (b), (q))
#else
#define VFMA(q, a, b) do { (q).x = fmaf((a).x, (b).x, (q).x); \
                           (q).y = fmaf((a).y, (b).y, (q).y); } while (0)
#endif

// Order-preserving fp32 -> uint32 (v1 > v2  <=>  key(v1) > key(v2))
__device__ __forceinline__ unsigned int fkey(float v) {
    unsigned int u = __float_as_uint(v);
    return (u & 0x80000000u) ? ~u : (u | 0x80000000u);
}

// ---------------- Kernel 1: normalize + per-row panel repack ----------------
// fiP: per-row panel [n][row][c2][x] float2 (channel-pair interleaved; halves of
//      16 c2 are 12288 B contiguous -> half-K DMA-able).
// frP: per-row panel [n][row][c][x] float scalar (halves of 32 c are 12288 B).
__global__ __launch_bounds__(256) void normalize_kernel(
    const float* __restrict__ f1, const float* __restrict__ f2,
    float2* __restrict__ fiP, float* __restrict__ frP, float* __restrict__ ssn)
{
    int t = blockIdx.x * 256 + threadIdx.x;
    const int perTensor = NITEM * HW;
    if (t >= 2 * perTensor) return;
    int which = t / perTensor;
    int p = t - which * perTensor;
    int n = p / HW;
    int pix = p - n * HW;
    const float* src = (which ? f2 : f1) + (size_t)n * C * HW + pix;
    float s = 0.f;
    #pragma unroll
    for (int c = 0; c < C; c++) {
        float v = src[c * HW];
        s = fmaf(v, v, s);
    }
    float norm = sqrtf(s);
    float scale = 1.0f / fmaxf(norm, 1e-12f);
    int y = pix / W, x = pix - y * W;
    if (which) {
        float* base = frP + ((size_t)n * H + y) * (C * W) + x;
        #pragma unroll
        for (int c = 0; c < C; c++)
            base[c * W] = src[c * HW] * scale;
        ssn[p] = s * scale * scale;
    } else {
        float2* base = fiP + ((size_t)n * H + y) * (32 * W) + x;
        #pragma unroll
        for (int c2 = 0; c2 < 32; c2++)
            base[c2 * W] = make_float2(src[(2 * c2) * HW] * scale,
                                       src[(2 * c2 + 1) * HW] * scale);
    }
}

// ---------------- Kernel 2: ref patch inverse norms ----------------
__global__ __launch_bounds__(256) void refnorm_kernel(
    const float* __restrict__ ssn, float* __restrict__ invn)
{
    int t = blockIdx.x * 256 + threadIdx.x;
    if (t >= NITEM * NP) return;
    int n = t / NP;
    int r = t - n * NP;
    int yr = r / HP, xr = r - yr * HP;
    const float* s = ssn + n * HW;
    float acc = 0.f;
    #pragma unroll
    for (int dy = 0; dy < 3; dy++)
        #pragma unroll
        for (int dx = 0; dx < 3; dx++)
            acc += s[(yr + dy) * W + (xr + dx)];
    invn[t] = 1.0f / (sqrtf(acc) + 1e-5f);
}

// ---- async half staging: A-half 12288 B + B-half 12288 B -> one 24576 B slot ----
// 24 chunks of 1024 B; wave wv issues chunks 6wv..6wv+5 (A region first, then B).
__device__ __forceinline__ void stage_half(const char* aH, const char* bH,
                                           char* slot, int wv, int lane)
{
#if defined(__has_builtin) && __has_builtin(__builtin_amdgcn_global_load_lds)
    #pragma unroll
    for (int c = 0; c < 6; ++c) {
        const int off = (wv * 6 + c) << 10;
        const char* g = ((off < 12288) ? (aH + off) : (bH + (off - 12288))) + lane * 16;
        __builtin_amdgcn_global_load_lds(
            (const __attribute__((address_space(1))) unsigned int*)(const void*)g,
            (__attribute__((address_space(3))) unsigned int*)(void*)(slot + off),
            16, 0, 0);
    }
#else
    #pragma unroll
    for (int c = 0; c < 6; ++c) {
        const int off = ((wv * 6 + c) << 10) + lane * 16;
        const char* g = (off < 12288) ? (aH + off) : (bH + (off - 12288));
        *(float4*)(slot + off) = *(const float4*)g;
    }
#endif
}

// ---------------- Kernel 3: fused row-pair GEMM + register diagonal taps + argmax ----
// R11 math (bit-identical association) on a counted-vmcnt half-K pipeline (T4):
// two 24.6 KB slots; per half-iteration:
//   raw s_barrier -> issue stage(k+1) into slot (k+1)&1 -> [row boundary: taps]
//   -> s_waitcnt vmcnt(6) (counted; stage(k+1) stays IN FLIGHT) -> GEMM half slot k&1.
// No vmcnt(0) in the loop (only last iteration). Hazards: slot reads/writes are
// disjoint buffers; cross-wave WAR fenced by the barrier (reads register-consumed
// before arrival); halo ds_write drained with explicit lgkmcnt(0) before the next
// raw barrier (raw s_barrier does NOT drain LDS). Channel order c2 = 0..15 then
// 16..31 == ascending-c chain -> bit-identical to all passing rounds.
// launch_bounds stays (256,2): (256,4) halves the VGPR budget and spills (R6).
__global__ __launch_bounds__(256, 2) void corr_fused_kernel(
    const float2* __restrict__ fiP, const float* __restrict__ frP,
    const float* __restrict__ invn, unsigned long long* __restrict__ best,
    unsigned int* __restrict__ tick)
{
    __shared__ struct {
        char  slot[2][24576];   // [A-half: f32x2[16][96] | B-half: float[32][96]]
        float sh[3][2][100];    // halo rows for wave-boundary groups
        int   sp;
    } sm;                       // ~51.6 KB -> 3 blocks/CU

    const int t = threadIdx.x;
    const int tu = t >> 4, tv = t & 15;     // 16x16 grid of 6x6 fragments
    const int lane = t & 63;
    const int quad = tu & 3;                // row-subgroup within wave
    const int wv = t >> 6;
    const int u0 = 6 * tu, v0 = 6 * tv;
    const unsigned long long gmask = 0xFFFFull << (lane & 48);

    const int n = blockIdx.x & 1;           // 384 blocks per item, XCD-interleaved

    const char* fiB = (const char*)(fiP + (size_t)n * H * (32 * W));  // 24576 B/row
    const char* frB = (const char*)(frP + (size_t)n * H * (C * W));   // 24576 B/row
    const float* inv = invn + (size_t)n * NP;
    unsigned long long* bn = best + (size_t)n * NP;

    float pA[6][6], pB[6][6];
    float acc[6][6];

    for (;;) {
        if (t == 0) sm.sp = (int)atomicAdd(&tick[n * 16], 1u);
        __syncthreads();
        const int uj = sm.sp;               // unit index within item
        if (uj >= UNITS_PER_N) break;

        // ---- decode unit -> (dy, ya, nb), center-out dy order ----
        int dy = 0, ya = 0, nb = 0;
        {
            int r = uj;
            for (int s = 0; s < 187; ++s) {
                int ady = (s + 1) >> 1;          // 0,1,1,2,2,...,93,93
                int nyi = 94 - ady;
                int q = (nyi + PL - 1) / PL;
                if (r < q) {
                    dy = (s & 1) ? -ady : ady;
                    ya = (dy < 0 ? -dy : 0) + r * PL;
                    nb = nyi - r * PL; if (nb > PL) nb = PL;
                    break;
                }
                r -= q;
            }
        }
        const int R = nb + 2;               // rows y = ya .. ya+R-1 (= yb+1)
        const int K = 2 * R;                // half-iterations

        // ---- taps + y-rotation + finalize for row y (verbatim R11 logic) ----
        auto do_taps = [&](int y) {
            const bool doFin = (y >= ya + 2);
            const bool doA = (y > ya);
            const int yi = y - 2;
            const int yr = yi + dy;

            float c6[6], c7[6];
            #pragma unroll
            for (int i = 0; i < 6; ++i) {
                c6[i] = __shfl_down(acc[i][0], 1);   // col u0+i, v0+6
                c7[i] = __shfl_down(acc[i][1], 1);   // col u0+i, v0+7
            }
            float e6[8], e7[8];
            #pragma unroll
            for (int jj = 0; jj < 6; ++jj) {
                e6[jj] = __shfl_down(acc[0][jj], 16);  // row u0+6
                e7[jj] = __shfl_down(acc[1][jj], 16);  // row u0+7
            }
            e6[6] = __shfl_down(acc[0][0], 17);
            e6[7] = __shfl_down(acc[0][1], 17);
            e7[6] = __shfl_down(acc[1][0], 17);
            e7[7] = __shfl_down(acc[1][1], 17);
            if (quad == 3) {
                if (tu < 15) {
                    const int g = tu >> 2;
                    #pragma unroll
                    for (int jj = 0; jj < 8; ++jj) {
                        e6[jj] = sm.sh[g][0][v0 + jj];
                        e7[jj] = sm.sh[g][1][v0 + jj];
                    }
                } else {
                    #pragma unroll
                    for (int jj = 0; jj < 8; ++jj) { e6[jj] = 0.f; e7[jj] = 0.f; }
                }
            }

            float ivr[6];
            if (doFin) {
                const float* ivp = inv + (size_t)yr * HP;
                #pragma unroll
                for (int jj = 0; jj < 6; ++jj) {
                    int xr = v0 + jj;
                    ivr[jj] = ivp[xr > 93 ? 93 : xr];   // clamp; garbage masked later
                }
            }

            #pragma unroll
            for (int i = 0; i < 6; ++i) {
                float bv = -INFINITY; int bxr = 0;
                #pragma unroll
                for (int jj = 0; jj < 6; ++jj) {
                    const int i1 = (i + 1 <= 5) ? i + 1 : 0;
                    const int j1 = (jj + 1 <= 5) ? jj + 1 : 0;
                    const int i2 = (i + 2 <= 5) ? i + 2 : 0;
                    const int j2 = (jj + 2 <= 5) ? jj + 2 : 0;
                    float E0 = acc[i][jj];
                    float E1 = (i + 1 <= 5)
                             ? ((jj + 1 <= 5) ? acc[i1][j1] : c6[i1])
                             : e6[jj + 1];
                    float E2 = (i + 2 <= 5)
                             ? ((jj + 2 <= 5) ? acc[i2][j2]
                                              : ((jj + 2 == 6) ? c6[i2] : c7[i2]))
                             : ((i + 2 == 6) ? e6[jj + 2] : e7[jj + 2]);
                    float bx = (E0 + E1) + E2;           // (g0+g1)+g2, as pass2
                    if (doFin) {
                        float v = (pA[i][jj] + bx) * ivr[jj];  // ((B0+B1)+B2)*inv
                        int xr = v0 + jj;
                        if (xr < HP && (u0 + i) < HP && v > bv) { bv = v; bxr = xr; }
                    }
                    if (doA) pA[i][jj] = pB[i][jj] + bx;
                    pB[i][jj] = bx;
                }
                if (doFin) {
                    float mx = bv;
                    #pragma unroll
                    for (int m = 1; m < 16; m <<= 1)
                        mx = fmaxf(mx, __shfl_xor(mx, m));   // 16-lane xr-group max
                    unsigned long long ball = __ballot(bv == mx) & gmask;
                    int srcl = __ffsll(ball) - 1;            // lowest lane = min xr
                    int wxr = __shfl(bxr, srcl);
                    if (tv == 0 && (u0 + i) < HP) {
                        unsigned long long key =
                            ((unsigned long long)fkey(mx) << 32)
                          | (unsigned int)(~(unsigned int)(yr * HP + wxr));
                        const size_t off = (size_t)yi * HP + (u0 + i);
                        if (key > bn[off]) atomicMax(&bn[off], key);  // monotone: stale-skip safe
                    }
                }
            }
        };

        // prologue: stage (row ya, half 0) -> slot 0
        stage_half(fiB + (size_t)ya * 24576,
                   frB + (size_t)(ya + dy) * 24576,
                   sm.slot[0], wv, lane);

        f32x2 q[6][3];
        for (int k = 0; k < K; ++k) {
            const int r = k >> 1, h = k & 1;
            const int y = ya + r;

            __builtin_amdgcn_s_barrier();   // raw: slot (k+1)&1 free; sh synced

            if (k + 1 < K) {                // issue next half into the other slot
                const int k1 = k + 1, r1 = k1 >> 1, h1 = k1 & 1;
                stage_half(fiB + (size_t)(ya + r1) * 24576 + h1 * 12288,
                           frB + (size_t)(ya + r1 + dy) * 24576 + h1 * 12288,
                           sm.slot[k1 & 1], wv, lane);
            }

            if (h == 0) {
                if (r >= 1) do_taps(y - 1);          // prev row (covers DMA latency)
                #pragma unroll
                for (int i = 0; i < 6; ++i)
                    #pragma unroll
                    for (int p = 0; p < 3; ++p) q[i][p] = (f32x2)(0.f);
            }

            // counted wait: stage(k) done; stage(k+1) stays in flight
            if (k + 1 < K) asm volatile("s_waitcnt vmcnt(6)" ::: "memory");
            else           asm volatile("s_waitcnt vmcnt(0)" ::: "memory");

            // ---- GEMM half: local channel pairs 0..15 (global c2 = 16h + c2l) ----
            {
                const char* base = sm.slot[k & 1];
                #pragma unroll 2
                for (int c2l = 0; c2l < 16; ++c2l) {
                    const float4* ap = (const float4*)(base + c2l * 768 + u0 * 8);
                    float4 A0 = ap[0], A1 = ap[1], A2 = ap[2];
                    const float* brow = (const float*)(base + 12288);
                    const f32x2* bpe = (const f32x2*)(brow + (2 * c2l) * 96 + v0);
                    const f32x2* bpo = (const f32x2*)(brow + (2 * c2l + 1) * 96 + v0);
                    f32x2 be0 = bpe[0], be1 = bpe[1], be2 = bpe[2];
                    f32x2 bo0 = bpo[0], bo1 = bpo[1], bo2 = bpo[2];
                    // even channel c = 2*(16h+c2l) (first in ascending-c chain)
                    f32x2 s0 = {A0.x, A0.x}, s1 = {A0.z, A0.z}, s2 = {A1.x, A1.x},
                          s3 = {A1.z, A1.z}, s4 = {A2.x, A2.x}, s5 = {A2.z, A2.z};
                    VFMA(q[0][0], s0, be0); VFMA(q[0][1], s0, be1); VFMA(q[0][2], s0, be2);
                    VFMA(q[1][0], s1, be0); VFMA(q[1][1], s1, be1); VFMA(q[1][2], s1, be2);
                    VFMA(q[2][0], s2, be0); VFMA(q[2][1], s2, be1); VFMA(q[2][2], s2, be2);
                    VFMA(q[3][0], s3, be0); VFMA(q[3][1], s3, be1); VFMA(q[3][2], s3, be2);
                    VFMA(q[4][0], s4, be0); VFMA(q[4][1], s4, be1); VFMA(q[4][2], s4, be2);
                    VFMA(q[5][0], s5, be0); VFMA(q[5][1], s5, be1); VFMA(q[5][2], s5, be2);
                    // odd channel (second)
                    f32x2 r0 = {A0.y, A0.y}, r1 = {A0.w, A0.w}, r2 = {A1.y, A1.y},
                          r3 = {A1.w, A1.w}, r4 = {A2.y, A2.y}, r5 = {A2.w, A2.w};
                    VFMA(q[0][0], r0, bo0); VFMA(q[0][1], r0, bo1); VFMA(q[0][2], r0, bo2);
                    VFMA(q[1][0], r1, bo0); VFMA(q[1][1], r1, bo1); VFMA(q[1][2], r1, bo2);
                    VFMA(q[2][0], r2, bo0); VFMA(q[2][1], r2, bo1); VFMA(q[2][2], r2, bo2);
                    VFMA(q[3][0], r3, bo0); VFMA(q[3][1], r3, bo1); VFMA(q[3][2], r3, bo2);
                    VFMA(q[4][0], r4, bo0); VFMA(q[4][1], r4, bo1); VFMA(q[4][2], r4, bo2);
                    VFMA(q[5][0], r5, bo0); VFMA(q[5][1], r5, bo1); VFMA(q[5][2], r5, bo2);
                }
            }

            if (h == 1) {                    // row complete: unpack acc, publish halo
                #pragma unroll
                for (int i = 0; i < 6; ++i)
                    #pragma unroll
                    for (int jj = 0; jj < 6; ++jj) acc[i][jj] = q[i][jj >> 1][jj & 1];
                if (quad == 0 && tu >= 4) {
                    const int g = (tu >> 2) - 1;
                    #pragma unroll
                    for (int jj = 0; jj < 6; ++jj) {
                        sm.sh[g][0][v0 + jj] = acc[0][jj];
                        sm.sh[g][1][v0 + jj] = acc[1][jj];
                    }
                }
                // raw s_barrier does NOT drain LDS: flush halo writes before next barrier
                asm volatile("s_waitcnt lgkmcnt(0)" ::: "memory");
            }
        }

        __builtin_amdgcn_s_barrier();        // halo of last row synced
        do_taps(ya + R - 1);                 // final row's taps/finalize
    }
}

// ---------------- Kernel 4: expand to 9 shifted copies, channel-interleaved ----------------
__global__ __launch_bounds__(256) void expand_best_kernel(
    const unsigned long long* __restrict__ best, float* __restrict__ out)
{
    int t = blockIdx.x * 256 + threadIdx.x;
    const int total = NITEM * 18 * HW;
    if (t >= total) return;
    int x = t % W;
    int y = (t / W) % H;
    int chn = (t / HW) % 18;
    int n = t / (18 * HW);
    int k = chn >> 1;
    int b = chn & 1;          // 0 -> flow_h, 1 -> flow_w
    int is = k / 3, js = k - is * 3;
    int ys = y - is, xs = x - js;
    float val = 0.f;
    if (ys >= 0 && ys < HP && xs >= 0 && xs < HP) {
        int i = ys * HP + xs;
        unsigned long long key = best[(size_t)n * NP + i];
        int idx = (int)(~(unsigned int)key);
        int yr = idx / HP, xr = idx - yr * HP;
        val = b ? (float)(xr - xs) : (float)(yr - ys);
    }
    out[t] = val;
}

// ---------------- Launch ----------------
extern "C" void kernel_launch(void* const* d_in, const int* in_sizes, int n_in,
                              void* d_out, int out_size, void* d_ws, size_t ws_size,
                              hipStream_t stream) {
    (void)in_sizes; (void)n_in; (void)out_size; (void)ws_size;
    const float* f1 = (const float*)d_in[0];
    const float* f2 = (const float*)d_in[1];

    float2* fiP = (float2*)d_ws;                            // 2*96*32*96 float2 = 4.7 MB
    float*  frP = (float*)(fiP + (size_t)NITEM * H * 32 * W);  // 4.7 MB
    float*  ssn = frP + (size_t)NITEM * H * C * W;
    float*  invn = ssn + (size_t)NITEM * HW;
    unsigned long long* best =
        (unsigned long long*)((((uintptr_t)(invn + (size_t)NITEM * NP)) + 63) & ~(uintptr_t)63);
    unsigned int* tick = (unsigned int*)(best + (size_t)NITEM * NP);  // 2 pools, 64B apart
    // total ~9.7 MB of workspace

    normalize_kernel<<<(2 * NITEM * HW + 255) / 256, 256, 0, stream>>>(f1, f2, fiP, frP, ssn);
    refnorm_kernel<<<(NITEM * NP + 255) / 256, 256, 0, stream>>>(ssn, invn);
    hipMemsetAsync(best, 0, (size_t)NITEM * NP * sizeof(unsigned long long) + 512, stream);
    corr_fused_kernel<<<NBLOCKS, 256, 0, stream>>>(fiP, frP, invn, best, tick);
    expand_best_kernel<<<(NITEM * 18 * HW + 255) / 256, 256, 0, stream>>>(best, (float*)d_out);
}